// Round 1
// baseline (304.896 us; speedup 1.0000x reference)
//
#include <hip/hip_runtime.h>

typedef unsigned short u16;
typedef unsigned int   u32;
typedef __bf16 bf16x8 __attribute__((ext_vector_type(8)));
typedef float  f32x4  __attribute__((ext_vector_type(4)));

#define NEG_INF (-__builtin_inff())

// async global->LDS, 16B per lane; LDS dest must be wave-uniform base + lane*16
#define GLDS16(g, l) __builtin_amdgcn_global_load_lds( \
    (const __attribute__((address_space(1))) void*)(g), \
    (__attribute__((address_space(3))) void*)(l), 16, 0, 0)

__device__ __forceinline__ u16 f2bf(float f) {      // RNE float->bf16
  u32 u = __builtin_bit_cast(u32, f);
  u32 r = u + 0x7FFFu + ((u >> 16) & 1u);
  return (u16)(r >> 16);
}
__device__ __forceinline__ float bf2f(u16 v) {
  u32 u = ((u32)v) << 16;
  return __builtin_bit_cast(float, u);
}

// ---------------------------------------------------------------------------
// dtype detect: bf16 N(0,1) data -> ~99% of u16 exponent fields in [118,129];
// fp32 data -> ~52% (high halves only). Threshold 75%.
// ---------------------------------------------------------------------------
__global__ void detect_kernel(const u16* __restrict__ q, int* __restrict__ flag) {
  __shared__ int cnt;
  if (threadIdx.x == 0) cnt = 0;
  __syncthreads();
  int local = 0;
  for (int i = threadIdx.x; i < 8192; i += 256) {
    int e = (q[i] >> 7) & 0xFF;
    if (e >= 118 && e <= 129) local++;
  }
  atomicAdd(&cnt, local);
  __syncthreads();
  if (threadIdx.x == 0) flag[0] = (cnt > 6144) ? 1 : 0;
}

// ---------------------------------------------------------------------------
// fused conversion of the 10 float tensors to canonical bf16 workspace
// unit = 8 elements (16B of bf16 output)
// seg sizes (units): q 524288 | k 524288 | W*4 131072 | b*4 128
// ---------------------------------------------------------------------------
struct ConvArgs {
  const void* src[10];
  u16* dst[10];
};

__global__ void convert_kernel(ConvArgs a, const int* __restrict__ flag) {
  const int fl = *flag;
  const int total = 1573376;
  for (int u0 = blockIdx.x * blockDim.x + threadIdx.x; u0 < total;
       u0 += gridDim.x * blockDim.x) {
    int s, off;
    if (u0 < 1048576)      { s = u0 >> 19;                 off = u0 & 524287; }
    else if (u0 < 1572864) { int v = u0 - 1048576; s = 2 + (v >> 17); off = v & 131071; }
    else                   { int v = u0 - 1572864; s = 6 + (v >> 7);  off = v & 127; }
    u16* d = a.dst[s] + (size_t)off * 8;
    if (fl) {
      const uint4* sp = (const uint4*)((const u16*)a.src[s] + (size_t)off * 8);
      *(uint4*)d = *sp;
    } else {
      const float* sp = (const float*)a.src[s] + (size_t)off * 8;
      u16 tmp[8];
      #pragma unroll
      for (int j = 0; j < 8; j++) tmp[j] = f2bf(sp[j]);
      *(uint4*)d = *(uint4*)tmp;
    }
  }
}

// ---------------------------------------------------------------------------
// 128x128 bf16 GEMM mainloop (NT: C[m,n] = sum_k A[m,k] * W[n,k]), K=1024
// m97 structure: global_load_lds width 16, 2 barriers / K-step, BK=32
// ---------------------------------------------------------------------------
__device__ __forceinline__ void gemm_mainloop_128(
    const u16* __restrict__ A, const u16* __restrict__ W,
    int bm, int bn, u16* As, u16* Bs, f32x4 acc[4][4]) {
  const int t = threadIdx.x, lane = t & 63, w = t >> 6;
  const int wm = (w >> 1) * 64, wn = (w & 1) * 64;
  const int l15 = lane & 15, quad = lane >> 4;
  const int sr = t >> 2, sc = (t & 3) * 8;
  const u16* Ag0 = A + (size_t)(bm + sr) * 1024 + sc;
  const u16* Ag1 = Ag0 + (size_t)64 * 1024;
  const u16* Wg0 = W + (size_t)(bn + sr) * 1024 + sc;
  const u16* Wg1 = Wg0 + (size_t)64 * 1024;
  u16* As0 = As + t * 8;        u16* As1 = As + 2048 + t * 8;
  u16* Bs0 = Bs + t * 8;        u16* Bs1 = Bs + 2048 + t * 8;

  for (int k0 = 0; k0 < 1024; k0 += 32) {
    GLDS16(Ag0 + k0, As0);
    GLDS16(Ag1 + k0, As1);
    GLDS16(Wg0 + k0, Bs0);
    GLDS16(Wg1 + k0, Bs1);
    __syncthreads();                       // drains vmcnt -> LDS tiles ready
    bf16x8 af[4], bw[4];
    #pragma unroll
    for (int i = 0; i < 4; i++) {
      af[i] = *(const bf16x8*)&As[(wm + i * 16 + l15) * 32 + quad * 8];
      bw[i] = *(const bf16x8*)&Bs[(wn + i * 16 + l15) * 32 + quad * 8];
    }
    #pragma unroll
    for (int i = 0; i < 4; i++)
      #pragma unroll
      for (int j = 0; j < 4; j++)
        acc[i][j] = __builtin_amdgcn_mfma_f32_16x16x32_bf16(af[i], bw[j], acc[i][j], 0, 0, 0);
    __syncthreads();                       // reads done before next stage
  }
}

// ---------------------------------------------------------------------------
// fused QKV projections. grid (8, 32, 3): z=0 Q, z=1 K, z=2 V (V input = k!)
// z<2: out [4096][1024] row-major. z==2: out Vt [b][h][64][2048] (d-major)
// ---------------------------------------------------------------------------
__global__ __launch_bounds__(256) void qkv_proj_kernel(
    const u16* __restrict__ qc, const u16* __restrict__ kc,
    const u16* __restrict__ Wq, const u16* __restrict__ Wk, const u16* __restrict__ Wv,
    const u16* __restrict__ bq, const u16* __restrict__ bk, const u16* __restrict__ bv,
    u16* __restrict__ Qp, u16* __restrict__ Kp, u16* __restrict__ Vt) {
  __shared__ __align__(16) u16 As[128 * 32];
  __shared__ __align__(16) u16 Bs[128 * 32];
  const int z = blockIdx.z;
  const u16* A    = (z == 0) ? qc : kc;
  const u16* W    = (z == 0) ? Wq : (z == 1) ? Wk : Wv;
  const u16* bias = (z == 0) ? bq : (z == 1) ? bk : bv;
  const int bm = blockIdx.y * 128, bn = blockIdx.x * 128;

  const f32x4 fzero = {0.f, 0.f, 0.f, 0.f};
  f32x4 acc[4][4];
  #pragma unroll
  for (int i = 0; i < 4; i++)
    #pragma unroll
    for (int j = 0; j < 4; j++) acc[i][j] = fzero;

  gemm_mainloop_128(A, W, bm, bn, As, Bs, acc);

  const int t = threadIdx.x, lane = t & 63, w = t >> 6;
  const int wm = (w >> 1) * 64, wn = (w & 1) * 64;
  const int l15 = lane & 15, quad = lane >> 4;

  if (z < 2) {
    u16* out = (z == 0) ? Qp : Kp;
    #pragma unroll
    for (int i = 0; i < 4; i++)
      #pragma unroll
      for (int j = 0; j < 4; j++) {
        int n = bn + wn + j * 16 + l15;
        float bb = bf2f(bias[n]);
        int m0 = bm + wm + i * 16 + quad * 4;
        #pragma unroll
        for (int r = 0; r < 4; r++)
          out[(size_t)(m0 + r) * 1024 + n] = f2bf(acc[i][j][r] + bb);
      }
  } else {
    #pragma unroll
    for (int i = 0; i < 4; i++)
      #pragma unroll
      for (int j = 0; j < 4; j++) {
        int n = bn + wn + j * 16 + l15;
        int hh = n >> 6, dw = n & 63;
        float bb = bf2f(bias[n]);
        int m0 = bm + wm + i * 16 + quad * 4;
        int b_ = m0 >> 11, s0 = m0 & 2047;
        u16 tmp[4];
        #pragma unroll
        for (int r = 0; r < 4; r++) tmp[r] = f2bf(acc[i][j][r] + bb);
        *(ushort4*)&Vt[((size_t)(b_ * 16 + hh) * 64 + dw) * 2048 + s0] = *(ushort4*)tmp;
      }
  }
}

// ---------------------------------------------------------------------------
// flash attention. grid (16, 32): x -> qt (reversed: heavy first), y -> (b,h)
// block 256 = 4 waves, each wave owns 32 q-rows. BQ=128, BKEY=128.
// LDS: PA = K-tile (128x72 padded) / Q-tile / P (4 x 32x136 padded)
//      VS = V-tile d-major (64x136 padded), kb = key-mask bias
// ---------------------------------------------------------------------------
__global__ __launch_bounds__(256) void attn_kernel(
    const u16* __restrict__ Qp, const u16* __restrict__ Kp, const u16* __restrict__ Vt,
    const int* __restrict__ qmask, const int* __restrict__ kmask,
    const int* __restrict__ causal_p, u16* __restrict__ AO) {
  __shared__ __align__(16) u16 PA[17408];
  __shared__ __align__(16) u16 VS[64 * 136];
  __shared__ float kb[128];

  const int t = threadIdx.x, lane = t & 63, w = t >> 6;
  const int quad = lane >> 4, l15 = lane & 15;
  const int qt = 15 - (int)blockIdx.x;
  const int bh = blockIdx.y, b = bh >> 4, h = bh & 15;
  const int causal = *causal_p;

  // ---- stage Q tile (padded stride 72), lift to registers ----
  const u16* qbase = Qp + (size_t)(b * 2048 + qt * 128) * 1024 + h * 64;
  #pragma unroll
  for (int i = 0; i < 4; i++) {
    int u = t + i * 256;
    int r = u >> 3, c8 = (u & 7) * 8;
    *(uint4*)&PA[r * 72 + c8] = *(const uint4*)&qbase[(size_t)r * 1024 + c8];
  }
  __syncthreads();
  bf16x8 qf[2][2];
  #pragma unroll
  for (int mt = 0; mt < 2; mt++)
    #pragma unroll
    for (int kk = 0; kk < 2; kk++)
      qf[mt][kk] = *(const bf16x8*)&PA[(w * 32 + mt * 16 + l15) * 72 + kk * 32 + quad * 8];
  __syncthreads();

  const f32x4 fzero = {0.f, 0.f, 0.f, 0.f};
  f32x4 Oa[2][4];
  float mr[2][4], lr[2][4];
  #pragma unroll
  for (int mt = 0; mt < 2; mt++) {
    #pragma unroll
    for (int nt = 0; nt < 4; nt++) Oa[mt][nt] = fzero;
    #pragma unroll
    for (int r = 0; r < 4; r++) { mr[mt][r] = NEG_INF; lr[mt][r] = 0.f; }
  }

  const u16* kbase0 = Kp + (size_t)(b * 2048) * 1024 + h * 64;
  const u16* vbase0 = Vt + (size_t)((b * 16 + h) * 64) * 2048;
  const int ktend = causal ? qt : 15;

  for (int kt = 0; kt <= ktend; kt++) {
    // ---- stage K (128x72), V (64x136), key-mask bias ----
    const u16* kbase = kbase0 + (size_t)(kt * 128) * 1024;
    #pragma unroll
    for (int i = 0; i < 4; i++) {
      int u = t + i * 256;
      int r = u >> 3, c8 = (u & 7) * 8;
      *(uint4*)&PA[r * 72 + c8] = *(const uint4*)&kbase[(size_t)r * 1024 + c8];
    }
    const u16* vbase = vbase0 + kt * 128;
    #pragma unroll
    for (int i = 0; i < 4; i++) {
      int u = t + i * 256;
      int d = u >> 4, c8 = (u & 15) * 8;
      *(uint4*)&VS[d * 136 + c8] = *(const uint4*)&vbase[(size_t)d * 2048 + c8];
    }
    if (t < 128) kb[t] = kmask[b * 2048 + kt * 128 + t] ? 0.0f : NEG_INF;
    __syncthreads();

    // ---- scores: S[32 x 128] per wave ----
    f32x4 sa[2][8];
    #pragma unroll
    for (int mt = 0; mt < 2; mt++)
      #pragma unroll
      for (int nt = 0; nt < 8; nt++) sa[mt][nt] = fzero;
    #pragma unroll
    for (int kk = 0; kk < 2; kk++)
      #pragma unroll
      for (int nt = 0; nt < 8; nt++) {
        bf16x8 kf = *(const bf16x8*)&PA[(nt * 16 + l15) * 72 + kk * 32 + quad * 8];
        sa[0][nt] = __builtin_amdgcn_mfma_f32_16x16x32_bf16(qf[0][kk], kf, sa[0][nt], 0, 0, 0);
        sa[1][nt] = __builtin_amdgcn_mfma_f32_16x16x32_bf16(qf[1][kk], kf, sa[1][nt], 0, 0, 0);
      }

    // ---- scale + masks (in log2 domain: cs = log2(e)/sqrt(64)) ----
    const float cs = 0.18033688011112042f;
    #pragma unroll
    for (int nt = 0; nt < 8; nt++) {
      float bias = kb[nt * 16 + l15];
      #pragma unroll
      for (int mt = 0; mt < 2; mt++)
        #pragma unroll
        for (int r = 0; r < 4; r++)
          sa[mt][nt][r] = sa[mt][nt][r] * cs + bias;
    }
    if (causal && kt == qt) {
      #pragma unroll
      for (int mt = 0; mt < 2; mt++)
        #pragma unroll
        for (int nt = 0; nt < 8; nt++) {
          int col = nt * 16 + l15;
          #pragma unroll
          for (int r = 0; r < 4; r++) {
            int row = w * 32 + mt * 16 + quad * 4 + r;
            if (col > row) sa[mt][nt][r] = NEG_INF;
          }
        }
    }

    // ---- online softmax (rows owned by quad; reduce across 16 lanes) ----
    float al[2][4];
    #pragma unroll
    for (int mt = 0; mt < 2; mt++)
      #pragma unroll
      for (int r = 0; r < 4; r++) {
        float v = sa[mt][0][r];
        #pragma unroll
        for (int nt = 1; nt < 8; nt++) v = fmaxf(v, sa[mt][nt][r]);
        #pragma unroll
        for (int s = 1; s < 16; s <<= 1) v = fmaxf(v, __shfl_xor(v, s, 16));
        float mn = fmaxf(mr[mt][r], v);
        float mc = fmaxf(mn, -3.0e38f);          // avoid -inf - -inf
        al[mt][r] = exp2f(mr[mt][r] - mc);
        mr[mt][r] = mn;
        float ssum = 0.f;
        #pragma unroll
        for (int nt = 0; nt < 8; nt++) {
          float p = exp2f(sa[mt][nt][r] - mc);
          sa[mt][nt][r] = p;
          ssum += p;
        }
        #pragma unroll
        for (int s = 1; s < 16; s <<= 1) ssum += __shfl_xor(ssum, s, 16);
        lr[mt][r] = lr[mt][r] * al[mt][r] + ssum;
      }

    #pragma unroll
    for (int mt = 0; mt < 2; mt++)
      #pragma unroll
      for (int nt = 0; nt < 4; nt++)
        #pragma unroll
        for (int r = 0; r < 4; r++)
          Oa[mt][nt][r] *= al[mt][r];

    __syncthreads();   // all waves finished reading K tile before P overwrites

    // ---- P: C-layout -> LDS (padded 136) -> A-layout (own-wave region) ----
    u16* Pw = &PA[w * (32 * 136)];
    #pragma unroll
    for (int mt = 0; mt < 2; mt++)
      #pragma unroll
      for (int nt = 0; nt < 8; nt++) {
        int col = nt * 16 + l15;
        #pragma unroll
        for (int r = 0; r < 4; r++)
          Pw[(mt * 16 + quad * 4 + r) * 136 + col] = f2bf(sa[mt][nt][r]);
      }
    asm volatile("s_waitcnt lgkmcnt(0)" ::: "memory");   // wave-local P visibility

    // ---- PV: O += P(32x128) * V(128x64) ----
    #pragma unroll
    for (int kp = 0; kp < 4; kp++) {
      bf16x8 pf0 = *(const bf16x8*)&Pw[(l15) * 136 + kp * 32 + quad * 8];
      bf16x8 pf1 = *(const bf16x8*)&Pw[(16 + l15) * 136 + kp * 32 + quad * 8];
      #pragma unroll
      for (int nt = 0; nt < 4; nt++) {
        bf16x8 vf = *(const bf16x8*)&VS[(nt * 16 + l15) * 136 + kp * 32 + quad * 8];
        Oa[0][nt] = __builtin_amdgcn_mfma_f32_16x16x32_bf16(pf0, vf, Oa[0][nt], 0, 0, 0);
        Oa[1][nt] = __builtin_amdgcn_mfma_f32_16x16x32_bf16(pf1, vf, Oa[1][nt], 0, 0, 0);
      }
    }
    __syncthreads();   // P + V reads done before next stage
  }

  // ---- epilogue: 1/l, q_mask, store AO [4096][1024] bf16 ----
  #pragma unroll
  for (int mt = 0; mt < 2; mt++)
    #pragma unroll
    for (int r = 0; r < 4; r++) {
      int s = qt * 128 + w * 32 + mt * 16 + quad * 4 + r;
      float f = (lr[mt][r] > 0.f) ? (1.0f / lr[mt][r]) : 0.f;
      if (qmask[b * 2048 + s] == 0) f = 0.f;
      size_t rowoff = (size_t)(b * 2048 + s) * 1024 + h * 64;
      #pragma unroll
      for (int nt = 0; nt < 4; nt++)
        AO[rowoff + nt * 16 + l15] = f2bf(Oa[mt][nt][r] * f);
    }
}

// ---------------------------------------------------------------------------
// final projection: out = AO @ Wo^T + bo ; store bf16 or fp32 per flag
// ---------------------------------------------------------------------------
__global__ __launch_bounds__(256) void oproj_kernel(
    const u16* __restrict__ AO, const u16* __restrict__ Wo, const u16* __restrict__ bo,
    void* __restrict__ out, const int* __restrict__ flag) {
  __shared__ __align__(16) u16 As[128 * 32];
  __shared__ __align__(16) u16 Bs[128 * 32];
  const int bm = blockIdx.y * 128, bn = blockIdx.x * 128;

  const f32x4 fzero = {0.f, 0.f, 0.f, 0.f};
  f32x4 acc[4][4];
  #pragma unroll
  for (int i = 0; i < 4; i++)
    #pragma unroll
    for (int j = 0; j < 4; j++) acc[i][j] = fzero;

  gemm_mainloop_128(AO, Wo, bm, bn, As, Bs, acc);

  const int t = threadIdx.x, lane = t & 63, w = t >> 6;
  const int wm = (w >> 1) * 64, wn = (w & 1) * 64;
  const int l15 = lane & 15, quad = lane >> 4;
  const int isbf = *flag;
  #pragma unroll
  for (int i = 0; i < 4; i++)
    #pragma unroll
    for (int j = 0; j < 4; j++) {
      int n = bn + wn + j * 16 + l15;
      float bb = bf2f(bo[n]);
      int m0 = bm + wm + i * 16 + quad * 4;
      #pragma unroll
      for (int r = 0; r < 4; r++) {
        float v = acc[i][j][r] + bb;
        size_t idx = (size_t)(m0 + r) * 1024 + n;
        if (isbf) ((u16*)out)[idx] = f2bf(v);
        else      ((float*)out)[idx] = v;
      }
    }
}

// ---------------------------------------------------------------------------
extern "C" void kernel_launch(void* const* d_in, const int* in_sizes, int n_in,
                              void* d_out, int out_size, void* d_ws, size_t ws_size,
                              hipStream_t stream) {
  (void)in_sizes; (void)n_in; (void)out_size; (void)ws_size;

  char* w = (char*)d_ws;
  int* flag = (int*)w;
  u16* qc  = (u16*)(w + 256);
  u16* kc  = qc  + 4194304;   // 4096*1024
  u16* Qp  = kc  + 4194304;
  u16* Kp  = Qp  + 4194304;
  u16* Vt  = Kp  + 4194304;   // [b][h][64][2048]
  u16* AO  = Vt  + 4194304;
  u16* Wqc = AO  + 4194304;
  u16* Wkc = Wqc + 1048576;
  u16* Wvc = Wkc + 1048576;
  u16* Woc = Wvc + 1048576;
  u16* bqc = Woc + 1048576;
  u16* bkc = bqc + 1024;
  u16* bvc = bkc + 1024;
  u16* boc = bvc + 1024;

  detect_kernel<<<1, 256, 0, stream>>>((const u16*)d_in[0], flag);

  ConvArgs ca;
  ca.src[0] = d_in[0];  ca.dst[0] = qc;
  ca.src[1] = d_in[1];  ca.dst[1] = kc;
  ca.src[2] = d_in[4];  ca.dst[2] = Wqc;
  ca.src[3] = d_in[6];  ca.dst[3] = Wkc;
  ca.src[4] = d_in[8];  ca.dst[4] = Wvc;
  ca.src[5] = d_in[10]; ca.dst[5] = Woc;
  ca.src[6] = d_in[5];  ca.dst[6] = bqc;
  ca.src[7] = d_in[7];  ca.dst[7] = bkc;
  ca.src[8] = d_in[9];  ca.dst[8] = bvc;
  ca.src[9] = d_in[11]; ca.dst[9] = boc;
  convert_kernel<<<1024, 256, 0, stream>>>(ca, flag);

  qkv_proj_kernel<<<dim3(8, 32, 3), 256, 0, stream>>>(
      qc, kc, Wqc, Wkc, Wvc, bqc, bkc, bvc, Qp, Kp, Vt);

  attn_kernel<<<dim3(16, 32), 256, 0, stream>>>(
      Qp, Kp, Vt, (const int*)d_in[2], (const int*)d_in[3],
      (const int*)d_in[12], AO);

  oproj_kernel<<<dim3(8, 32), 256, 0, stream>>>(AO, Woc, boc, d_out, flag);
}